// Round 10
// baseline (27.144 us; speedup 1.0000x reference)
//
#include <hip/hip_runtime.h>
#include <math.h>

#define NBLK 1024   // main kernel: 262144 threads, 1 column each (R6/R8 topology)
#define NTHR 256

constexpr float LOG_K_F = 2.7725887222397811f;   // log(16)
constexpr float LOG_EPS = -69.077552789821368f;  // log(1e-30)
constexpr float LOG_001 = -6.9077552789821368f;  // log(0.001)

struct BC {
    float rb;        // exp(ev_oth - ev_cat): gumbel ratio threshold
    float qs, qo, eqs, eqo;
    float evt_cat, evt_oth;
    float C1;        // exp(dt1 - logK) (0 if t==0)
    float e_ct1;     // exp(ct1) (1 if t==0)
    float klp;       // prior-KL per-column constant
    int t0;
};

__device__ __forceinline__ float lae_f(float a, float b) {
    float m = fmaxf(a, b);
    return m + __logf(1.f + __expf(-fabsf(a - b)));
}

// Closed-form cosine-beta schedule constants (validated absmax 0.0 R4-R9).
// ac_raw(x) = sin^2(W*(1000-x)), W=pi/2016; log_cum telescopes; t=999 is the
// only beta-clip (beta=0.999).
__device__ __forceinline__ BC make_bc(int tb) {
    const float W = (float)(3.14159265358979323846 / 2016.0);
    const float s1000 = __sinf(W * 1000.f);
    const float ls1000 = __logf(s1000);
    const float inv2 = 1.f / (s1000 * s1000);

    const bool t999 = (tb == 999);
    const bool t0 = (tb == 0);
    const float ftb = (float)tb;

    const float ftbc = t999 ? 998.f : ftb;
    float ct = 2.f * (__logf(__sinf(W * (999.f - ftbc))) - ls1000);
    if (t999) ct += LOG_001;
    float dt = __logf(__sinf(W * (1999.f - ftb)) * __sinf(W * (ftb + 1.f)) * inv2 + 1e-40f);
    float at, btv;
    if (t999) {
        at = LOG_001;
        btv = __logf(0.999f);
    } else {
        const float s0 = __sinf(W * (1000.f - ftb));
        at = 2.f * (__logf(__sinf(W * (999.f - ftb))) - __logf(s0));
        btv = __logf(__sinf(W) * __sinf(W * (1999.f - 2.f * ftb)) / (s0 * s0) + 1e-40f);
    }
    float ct1 = 0.f, dt1 = 0.f;
    if (!t0) {
        ct1 = 2.f * (__logf(__sinf(W * (1000.f - ftb))) - ls1000);
        dt1 = __logf(__sinf(W * (2000.f - ftb)) * __sinf(W * ftb) * inv2 + 1e-40f);
    }

    const float ev_cat = lae_f(ct, dt - LOG_K_F);
    const float ev_oth = lae_f(LOG_EPS + ct, dt - LOG_K_F);

    BC c;
    c.t0 = t0 ? 1 : 0;
    c.rb = __expf(ev_oth - ev_cat);
    c.qs = lae_f(at, btv - LOG_K_F);
    c.qo = lae_f(LOG_EPS + at, btv - LOG_K_F);
    c.eqs = __expf(c.qs);
    c.eqo = __expf(c.qo);
    c.evt_cat = t0 ? 0.f : lae_f(ct1, dt1 - LOG_K_F);
    c.evt_oth = t0 ? LOG_EPS : lae_f(LOG_EPS + ct1, dt1 - LOG_K_F);
    c.C1 = t0 ? 0.f : __expf(dt1 - LOG_K_F);
    c.e_ct1 = t0 ? 1.f : __expf(ct1);
    const float cT = 2.f * (__logf(__sinf(W)) - ls1000) + LOG_001;
    const float dT = 0.f;
    const float vc = lae_f(cT, dT - LOG_K_F);
    const float vo = lae_f(LOG_EPS + cT, dT - LOG_K_F);
    c.klp = __expf(vc) * (vc + LOG_K_F) + 15.f * __expf(vo) * (vo + LOG_K_F);
    return c;
}

// Kernel 1: per-batch constants + zero the output accumulator (runs before
// main; graph edge guarantees visibility). Keeps the branchy transcendental
// blob out of the hot kernel (R3/R4 spill root cause).
__global__ void bc_kernel(const int* __restrict__ tarr, BC* __restrict__ bc,
                          float* __restrict__ out) {
    const int t = threadIdx.x;
    if (t < 64) bc[t] = make_bc(tarr[t]);
    if (t == 64) out[0] = 0.f;
}

// Kernel 2: R8's proven body; block sum lands via one device-scope
// atomicAdd per block (NO __threadfence / counter: that pattern cost ~17us
// in R3-R5 -- per-block L2 writeback). 1024 same-address f32 atomics
// pipeline against execution; ordering noise ~1e-7 << 0.1625 threshold.
__global__ __launch_bounds__(NTHR) void main_kernel(
        const int*   __restrict__ cats,     // [64,16,256]
        const float* __restrict__ logits,   // [64,256,256]
        const float* __restrict__ mnum,     // [64,8,256]
        const float* __restrict__ nnum,     // [64,8,256]
        const float* __restrict__ unoise,   // [64,256,256]
        const BC*    __restrict__ bc,       // [64]
        float*       __restrict__ out)
{
    const int tid = blockIdx.x * NTHR + threadIdx.x;  // 0..262143
    const int bi  = tid >> 8;                         // b*16 + i (== blockIdx.x)
    const int b   = bi >> 4;                          // block-uniform
    const BC c = bc[b];

    const int cat = cats[tid];
    const size_t base = (size_t)bi * 4096 + (tid & 255);

    // ---- load cluster: 32 independent coalesced loads, no compute between ----
    float uu[16], lg[16];
#pragma unroll
    for (int k = 0; k < 16; ++k) {
        uu[k] = unoise[base + (size_t)k * 256];
        lg[k] = logits[base + (size_t)k * 256];
    }

    // ---- softmax exponentials + gumbel-argmax candidates ----
    float ek[16];
    float slg = 0.f, u_cat = 0.f, umax = -1.f;
    int kmx = 0;
#pragma unroll
    for (int k = 0; k < 16; ++k) {
        ek[k] = __expf(lg[k]);
        slg += ek[k];
        const bool ic = (k == cat);
        u_cat = ic ? uu[k] : u_cat;
        const bool upd = (!ic) && (uu[k] > umax);
        umax = upd ? uu[k] : umax;
        kmx  = upd ? k : kmx;
    }
    // gumbel-argmax in ratio form: v_c > v_o  <=>  e_o > e_c * rb
    const float e_c = -__logf(u_cat + 1e-30f) + 1e-30f;
    const float e_o = -__logf(umax  + 1e-30f) + 1e-30f;
    const float thr = e_c * c.rb;
    const int samp = (e_o > thr) ? cat : ((e_o < thr) ? kmx : min(cat, kmx));

    // ---- model posterior in exp space ----
    const float scale = c.e_ct1 * __builtin_amdgcn_rcpf(slg);
    float ve_[16];
    float S_all = 0.f;
#pragma unroll
    for (int k = 0; k < 16; ++k) {
        ve_[k] = ek[k] * scale + c.C1;   // exp(evm_k), in (0, 1.1]
        S_all += ve_[k];
    }
    // sum_le via 4 grouped products (4 logs instead of 16); group product
    // >= (1e-7)^4 = 1e-28 > FLT_MIN, no underflow.
    float sum_le = 0.f;
#pragma unroll
    for (int gq = 0; gq < 4; ++gq) {
        const float p = ve_[4*gq] * ve_[4*gq+1] * ve_[4*gq+2] * ve_[4*gq+3];
        sum_le += __logf(p);
    }
    float ve_cat = ve_[0], ve_samp = ve_[0];
#pragma unroll
    for (int k = 0; k < 16; ++k) {
        ve_cat  = (k == cat)  ? ve_[k] : ve_cat;
        ve_samp = (k == samp) ? ve_[k] : ve_samp;
    }
    const float le_cat  = __logf(ve_cat);
    const float le_samp = __logf(ve_samp);
    const float sum_m = c.eqo * (S_all - ve_samp) + c.eqs * ve_samp;
    const float lsem  = __logf(sum_m);

    // ---- true posterior: <=3 distinct values, closed-form ----
    const bool  eq  = (cat == samp);
    const float q_c = eq ? c.qs : c.qo;
    const float w_s = eq ? 0.f : 1.f;
    const float n_o = eq ? 15.f : 14.f;
    const float a  = c.evt_cat + q_c;
    const float bs = c.evt_oth + c.qs;
    const float cc = c.evt_oth + c.qo;
    const float m  = fmaxf(a, fmaxf(bs, cc));
    const float ea = __expf(a - m), eb = __expf(bs - m), ecx = __expf(cc - m);
    const float D  = ea + w_s * eb + n_o * ecx;
    const float lset = m + __logf(D);
    const float rcpD = __builtin_amdgcn_rcpf(D);
    const float lt_c = a - lset, lt_s = bs - lset, lt_o = cc - lset;
    const float p_c = ea * rcpD, p_s = eb * rcpD, p_o = ecx * rcpD;

    const float sum_p_lt = p_c * lt_c + w_s * p_s * lt_s + n_o * p_o * lt_o;
    const float lm_cat  = le_cat  + q_c  - lsem;
    const float lm_samp = le_samp + c.qs - lsem;
    const float sum_lm_oth = (sum_le - le_cat - w_s * le_samp) + n_o * (c.qo - lsem);
    const float sum_p_lm = p_c * lm_cat + w_s * p_s * lm_samp + p_o * sum_lm_oth;
    const float kl  = sum_p_lt - sum_p_lm;
    const float nll = -lm_cat;

    float acc = ((c.t0 ? nll : kl) + c.klp) * (0.5f / 64.0f);

    // ---- numeric branch MSE (tids 0..131071) ----
    if (tid < 64 * 8 * 256) {
        const float d = mnum[tid] - nnum[tid];
        acc += d * d * (0.5f / 131072.f);
    }

    // ---- block reduction + one atomic per block ----
    for (int o = 32; o > 0; o >>= 1) acc += __shfl_down(acc, o, 64);
    __shared__ float wsum[4];
    const int wave = threadIdx.x >> 6, lane = threadIdx.x & 63;
    if (lane == 0) wsum[wave] = acc;
    __syncthreads();
    if (threadIdx.x == 0)
        atomicAdd(out, wsum[0] + wsum[1] + wsum[2] + wsum[3]);
}

extern "C" void kernel_launch(void* const* d_in, const int* in_sizes, int n_in,
                              void* d_out, int out_size, void* d_ws, size_t ws_size,
                              hipStream_t stream) {
    const int*   cats   = (const int*)  d_in[0];
    const float* logits = (const float*)d_in[1];
    const float* mnum   = (const float*)d_in[2];
    const float* nnum   = (const float*)d_in[3];
    const float* unoise = (const float*)d_in[4];
    const int*   tarr   = (const int*)  d_in[5];
    float* out = (float*)d_out;

    BC* bc = (BC*)d_ws;

    bc_kernel<<<1, 128, 0, stream>>>(tarr, bc, out);
    main_kernel<<<NBLK, NTHR, 0, stream>>>(cats, logits, mnum, nnum, unoise,
                                           bc, out);
}

// Round 11
// 27.035 us; speedup vs baseline: 1.0040x; 1.0040x over previous
//
#include <hip/hip_runtime.h>
#include <math.h>

#define NBLK 1024   // main kernel: 262144 threads, 1 column each (R6/R8 topology)
#define NTHR 256

constexpr float LOG_K_F = 2.7725887222397811f;   // log(16)
constexpr float LOG_EPS = -69.077552789821368f;  // log(1e-30)
constexpr float LOG_001 = -6.9077552789821368f;  // log(0.001)
constexpr float FPSCALE = 1073741824.0f;         // 2^30 fixed-point scale

struct BC {
    float rb;        // exp(ev_oth - ev_cat): gumbel ratio threshold
    float qs, qo, eqs, eqo;
    float evt_cat, evt_oth;
    float C1;        // exp(dt1 - logK) (0 if t==0)
    float e_ct1;     // exp(ct1) (1 if t==0)
    float klp;       // prior-KL per-column constant
    int t0;
};

__device__ __forceinline__ float lae_f(float a, float b) {
    float m = fmaxf(a, b);
    return m + __logf(1.f + __expf(-fabsf(a - b)));
}

// Closed-form cosine-beta schedule constants (validated absmax 0.0 R4-R10).
__device__ __forceinline__ BC make_bc(int tb) {
    const float W = (float)(3.14159265358979323846 / 2016.0);
    const float s1000 = __sinf(W * 1000.f);
    const float ls1000 = __logf(s1000);
    const float inv2 = 1.f / (s1000 * s1000);

    const bool t999 = (tb == 999);
    const bool t0 = (tb == 0);
    const float ftb = (float)tb;

    const float ftbc = t999 ? 998.f : ftb;
    float ct = 2.f * (__logf(__sinf(W * (999.f - ftbc))) - ls1000);
    if (t999) ct += LOG_001;
    float dt = __logf(__sinf(W * (1999.f - ftb)) * __sinf(W * (ftb + 1.f)) * inv2 + 1e-40f);
    float at, btv;
    if (t999) {
        at = LOG_001;
        btv = __logf(0.999f);
    } else {
        const float s0 = __sinf(W * (1000.f - ftb));
        at = 2.f * (__logf(__sinf(W * (999.f - ftb))) - __logf(s0));
        btv = __logf(__sinf(W) * __sinf(W * (1999.f - 2.f * ftb)) / (s0 * s0) + 1e-40f);
    }
    float ct1 = 0.f, dt1 = 0.f;
    if (!t0) {
        ct1 = 2.f * (__logf(__sinf(W * (1000.f - ftb))) - ls1000);
        dt1 = __logf(__sinf(W * (2000.f - ftb)) * __sinf(W * ftb) * inv2 + 1e-40f);
    }

    const float ev_cat = lae_f(ct, dt - LOG_K_F);
    const float ev_oth = lae_f(LOG_EPS + ct, dt - LOG_K_F);

    BC c;
    c.t0 = t0 ? 1 : 0;
    c.rb = __expf(ev_oth - ev_cat);
    c.qs = lae_f(at, btv - LOG_K_F);
    c.qo = lae_f(LOG_EPS + at, btv - LOG_K_F);
    c.eqs = __expf(c.qs);
    c.eqo = __expf(c.qo);
    c.evt_cat = t0 ? 0.f : lae_f(ct1, dt1 - LOG_K_F);
    c.evt_oth = t0 ? LOG_EPS : lae_f(LOG_EPS + ct1, dt1 - LOG_K_F);
    c.C1 = t0 ? 0.f : __expf(dt1 - LOG_K_F);
    c.e_ct1 = t0 ? 1.f : __expf(ct1);
    const float cT = 2.f * (__logf(__sinf(W)) - ls1000) + LOG_001;
    const float dT = 0.f;
    const float vc = lae_f(cT, dT - LOG_K_F);
    const float vo = lae_f(LOG_EPS + cT, dT - LOG_K_F);
    c.klp = __expf(vc) * (vc + LOG_K_F) + 15.f * __expf(vo) * (vo + LOG_K_F);
    return c;
}

// Kernel 1: per-batch constants + zero the packed accumulator (graph edge
// orders this before main). Keeps the transcendental blob out of the hot
// kernel (R3/R4 spill root cause).
__global__ void bc_kernel(const int* __restrict__ tarr, BC* __restrict__ bc,
                          unsigned long long* __restrict__ acc) {
    const int t = threadIdx.x;
    if (t < 64) bc[t] = make_bc(tarr[t]);
    if (t == 64) *acc = 0ull;
}

// Kernel 2: R9's proven body. Cross-block combine: ONE packed uint64 atomic
// per block into d_ws (VRAM, L2-cached -- d_out atomics cost 9us in R10).
// enc = (1<<52) | fp30(bsum+1). The RETURN VALUE alone identifies the last
// block (old>>52==1023) and yields the exact total (old+enc): no fence, no
// partials re-read, bit-deterministic (integer add is commutative).
__global__ __launch_bounds__(NTHR) void main_kernel(
        const int*   __restrict__ cats,     // [64,16,256]
        const float* __restrict__ logits,   // [64,256,256]
        const float* __restrict__ mnum,     // [64,8,256]
        const float* __restrict__ nnum,     // [64,8,256]
        const float* __restrict__ unoise,   // [64,256,256]
        const BC*    __restrict__ bc,       // [64]
        unsigned long long* __restrict__ acc_ws,
        float*       __restrict__ out)
{
    const int tid = blockIdx.x * NTHR + threadIdx.x;  // 0..262143
    const int bi  = tid >> 8;                         // b*16 + i (== blockIdx.x)
    const int b   = bi >> 4;                          // block-uniform
    const BC c = bc[b];

    const int cat = cats[tid];
    const size_t base = (size_t)bi * 4096 + (tid & 255);

    // ---- load cluster: 32 independent coalesced loads ----
    float uu[16], lg[16];
#pragma unroll
    for (int k = 0; k < 16; ++k) {
        uu[k] = unoise[base + (size_t)k * 256];
        lg[k] = logits[base + (size_t)k * 256];
    }

    // ---- softmax exponentials + gumbel-argmax candidates ----
    float ek[16];
    float slg = 0.f, u_cat = 0.f, umax = -1.f;
    int kmx = 0;
#pragma unroll
    for (int k = 0; k < 16; ++k) {
        ek[k] = __expf(lg[k]);
        slg += ek[k];
        const bool ic = (k == cat);
        u_cat = ic ? uu[k] : u_cat;
        const bool upd = (!ic) && (uu[k] > umax);
        umax = upd ? uu[k] : umax;
        kmx  = upd ? k : kmx;
    }
    // gumbel-argmax in ratio form: v_c > v_o  <=>  e_o > e_c * rb
    const float e_c = -__logf(u_cat + 1e-30f) + 1e-30f;
    const float e_o = -__logf(umax  + 1e-30f) + 1e-30f;
    const float thr = e_c * c.rb;
    const int samp = (e_o > thr) ? cat : ((e_o < thr) ? kmx : min(cat, kmx));

    // ---- model posterior in exp space ----
    const float scale = c.e_ct1 * __builtin_amdgcn_rcpf(slg);
    float ve_[16];
    float S_all = 0.f;
#pragma unroll
    for (int k = 0; k < 16; ++k) {
        ve_[k] = ek[k] * scale + c.C1;   // exp(evm_k), in (0, 1.1]
        S_all += ve_[k];
    }
    // sum_le via 4 grouped products (4 logs instead of 16)
    float sum_le = 0.f;
#pragma unroll
    for (int gq = 0; gq < 4; ++gq) {
        const float p = ve_[4*gq] * ve_[4*gq+1] * ve_[4*gq+2] * ve_[4*gq+3];
        sum_le += __logf(p);
    }
    float ve_cat = ve_[0], ve_samp = ve_[0];
#pragma unroll
    for (int k = 0; k < 16; ++k) {
        ve_cat  = (k == cat)  ? ve_[k] : ve_cat;
        ve_samp = (k == samp) ? ve_[k] : ve_samp;
    }
    const float le_cat  = __logf(ve_cat);
    const float le_samp = __logf(ve_samp);
    const float sum_m = c.eqo * (S_all - ve_samp) + c.eqs * ve_samp;
    const float lsem  = __logf(sum_m);

    // ---- true posterior: <=3 distinct values, closed-form ----
    const bool  eq  = (cat == samp);
    const float q_c = eq ? c.qs : c.qo;
    const float w_s = eq ? 0.f : 1.f;
    const float n_o = eq ? 15.f : 14.f;
    const float a  = c.evt_cat + q_c;
    const float bs = c.evt_oth + c.qs;
    const float cc = c.evt_oth + c.qo;
    const float m  = fmaxf(a, fmaxf(bs, cc));
    const float ea = __expf(a - m), eb = __expf(bs - m), ecx = __expf(cc - m);
    const float D  = ea + w_s * eb + n_o * ecx;
    const float lset = m + __logf(D);
    const float rcpD = __builtin_amdgcn_rcpf(D);
    const float lt_c = a - lset, lt_s = bs - lset, lt_o = cc - lset;
    const float p_c = ea * rcpD, p_s = eb * rcpD, p_o = ecx * rcpD;

    const float sum_p_lt = p_c * lt_c + w_s * p_s * lt_s + n_o * p_o * lt_o;
    const float lm_cat  = le_cat  + q_c  - lsem;
    const float lm_samp = le_samp + c.qs - lsem;
    const float sum_lm_oth = (sum_le - le_cat - w_s * le_samp) + n_o * (c.qo - lsem);
    const float sum_p_lm = p_c * lm_cat + w_s * p_s * lm_samp + p_o * sum_lm_oth;
    const float kl  = sum_p_lt - sum_p_lm;
    const float nll = -lm_cat;

    float acc = ((c.t0 ? nll : kl) + c.klp) * (0.5f / 64.0f);

    // ---- numeric branch MSE (tids 0..131071) ----
    if (tid < 64 * 8 * 256) {
        const float d = mnum[tid] - nnum[tid];
        acc += d * d * (0.5f / 131072.f);
    }

    // ---- block reduction + one packed atomic per block ----
    for (int o = 32; o > 0; o >>= 1) acc += __shfl_down(acc, o, 64);
    __shared__ float wsum[4];
    const int wave = threadIdx.x >> 6, lane = threadIdx.x & 63;
    if (lane == 0) wsum[wave] = acc;
    __syncthreads();
    if (threadIdx.x == 0) {
        const float bsum = wsum[0] + wsum[1] + wsum[2] + wsum[3];
        // bsum in (0, ~0.02]; +1 bias keeps encoding positive-robust
        const unsigned long long fp =
            (unsigned long long)((bsum + 1.0f) * FPSCALE);
        const unsigned long long enc = (1ull << 52) | fp;
        const unsigned long long old = atomicAdd(acc_ws, enc);
        if ((old >> 52) == (unsigned long long)(NBLK - 1)) {
            const unsigned long long tot = (old + enc) & ((1ull << 52) - 1ull);
            out[0] = (float)((double)tot / (double)FPSCALE - (double)NBLK);
        }
    }
}

extern "C" void kernel_launch(void* const* d_in, const int* in_sizes, int n_in,
                              void* d_out, int out_size, void* d_ws, size_t ws_size,
                              hipStream_t stream) {
    const int*   cats   = (const int*)  d_in[0];
    const float* logits = (const float*)d_in[1];
    const float* mnum   = (const float*)d_in[2];
    const float* nnum   = (const float*)d_in[3];
    const float* unoise = (const float*)d_in[4];
    const int*   tarr   = (const int*)  d_in[5];
    float* out = (float*)d_out;

    BC* bc = (BC*)d_ws;
    unsigned long long* acc_ws =
        (unsigned long long*)((char*)d_ws + 4096);

    bc_kernel<<<1, 128, 0, stream>>>(tarr, bc, acc_ws);
    main_kernel<<<NBLK, NTHR, 0, stream>>>(cats, logits, mnum, nnum, unoise,
                                           bc, acc_ws, out);
}

// Round 12
// 13.408 us; speedup vs baseline: 2.0244x; 2.0163x over previous
//
#include <hip/hip_runtime.h>
#include <math.h>

#define NBLK 1024   // main kernel: 262144 threads, 1 column each (R6/R8/R9 topology)
#define NTHR 256

constexpr float LOG_K_F = 2.7725887222397811f;   // log(16)
constexpr float LOG_EPS = -69.077552789821368f;  // log(1e-30)
constexpr float LOG_001 = -6.9077552789821368f;  // log(0.001)

struct BC {
    float rb;        // exp(ev_oth - ev_cat): gumbel ratio threshold
    float qs, qo, eqs, eqo;
    float evt_cat, evt_oth;
    float C1;        // exp(dt1 - logK) (0 if t==0)
    float e_ct1;     // exp(ct1) (1 if t==0)
    float klp;       // prior-KL per-column constant
    int t0;
};

__device__ __forceinline__ float lae_f(float a, float b) {
    float m = fmaxf(a, b);
    return m + __logf(1.f + __expf(-fabsf(a - b)));
}

// Closed-form cosine-beta schedule constants (validated absmax 0.0 R4-R11).
// ac_raw(x) = sin^2(W*(1000-x)), W=pi/2016; log_cum telescopes; t=999 is the
// only beta-clip (beta=0.999).
__device__ __forceinline__ BC make_bc(int tb) {
    const float W = (float)(3.14159265358979323846 / 2016.0);
    const float s1000 = __sinf(W * 1000.f);
    const float ls1000 = __logf(s1000);
    const float inv2 = 1.f / (s1000 * s1000);

    const bool t999 = (tb == 999);
    const bool t0 = (tb == 0);
    const float ftb = (float)tb;

    const float ftbc = t999 ? 998.f : ftb;
    float ct = 2.f * (__logf(__sinf(W * (999.f - ftbc))) - ls1000);
    if (t999) ct += LOG_001;
    float dt = __logf(__sinf(W * (1999.f - ftb)) * __sinf(W * (ftb + 1.f)) * inv2 + 1e-40f);
    float at, btv;
    if (t999) {
        at = LOG_001;
        btv = __logf(0.999f);
    } else {
        const float s0 = __sinf(W * (1000.f - ftb));
        at = 2.f * (__logf(__sinf(W * (999.f - ftb))) - __logf(s0));
        btv = __logf(__sinf(W) * __sinf(W * (1999.f - 2.f * ftb)) / (s0 * s0) + 1e-40f);
    }
    float ct1 = 0.f, dt1 = 0.f;
    if (!t0) {
        ct1 = 2.f * (__logf(__sinf(W * (1000.f - ftb))) - ls1000);
        dt1 = __logf(__sinf(W * (2000.f - ftb)) * __sinf(W * ftb) * inv2 + 1e-40f);
    }

    const float ev_cat = lae_f(ct, dt - LOG_K_F);
    const float ev_oth = lae_f(LOG_EPS + ct, dt - LOG_K_F);

    BC c;
    c.t0 = t0 ? 1 : 0;
    c.rb = __expf(ev_oth - ev_cat);
    c.qs = lae_f(at, btv - LOG_K_F);
    c.qo = lae_f(LOG_EPS + at, btv - LOG_K_F);
    c.eqs = __expf(c.qs);
    c.eqo = __expf(c.qo);
    c.evt_cat = t0 ? 0.f : lae_f(ct1, dt1 - LOG_K_F);
    c.evt_oth = t0 ? LOG_EPS : lae_f(LOG_EPS + ct1, dt1 - LOG_K_F);
    c.C1 = t0 ? 0.f : __expf(dt1 - LOG_K_F);
    c.e_ct1 = t0 ? 1.f : __expf(ct1);
    const float cT = 2.f * (__logf(__sinf(W)) - ls1000) + LOG_001;
    const float dT = 0.f;
    const float vc = lae_f(cT, dT - LOG_K_F);
    const float vo = lae_f(LOG_EPS + cT, dT - LOG_K_F);
    c.klp = __expf(vc) * (vc + LOG_K_F) + 15.f * __expf(vo) * (vo + LOG_K_F);
    return c;
}

// Kernel 1: R9's proven body, with BC computed per block by ONE lane into
// LDS (replaces the separate bc_kernel dispatch). NOT the R3/R4 failure:
// there every thread inlined make_bc and the compiler picked a 32-44 VGPR
// occupancy target, spilling ek[16]. Here __launch_bounds__(,4) grants a
// 128-VGPR budget (16 waves/CU -- the proven-good occupancy) so no spill.
__global__ __launch_bounds__(NTHR, 4) void main_kernel(
        const int*   __restrict__ cats,     // [64,16,256]
        const float* __restrict__ logits,   // [64,256,256]
        const float* __restrict__ mnum,     // [64,8,256]
        const float* __restrict__ nnum,     // [64,8,256]
        const float* __restrict__ unoise,   // [64,256,256]
        const int*   __restrict__ tarr,     // [64]
        float*       __restrict__ partials) // [NBLK]
{
    __shared__ BC sbc;
    const int tid = blockIdx.x * NTHR + threadIdx.x;  // 0..262143
    const int bi  = tid >> 8;                         // b*16 + i (== blockIdx.x)
    const int b   = bi >> 4;                          // block-uniform

    if (threadIdx.x == 0) sbc = make_bc(tarr[b]);

    const int cat = cats[tid];
    const size_t base = (size_t)bi * 4096 + (tid & 255);

    // ---- load cluster: 32 independent coalesced loads (overlaps BC calc) ----
    float uu[16], lg[16];
#pragma unroll
    for (int k = 0; k < 16; ++k) {
        uu[k] = unoise[base + (size_t)k * 256];
        lg[k] = logits[base + (size_t)k * 256];
    }
    __syncthreads();
    const BC c = sbc;

    // ---- softmax exponentials + gumbel-argmax candidates ----
    float ek[16];
    float slg = 0.f, u_cat = 0.f, umax = -1.f;
    int kmx = 0;
#pragma unroll
    for (int k = 0; k < 16; ++k) {
        ek[k] = __expf(lg[k]);
        slg += ek[k];
        const bool ic = (k == cat);
        u_cat = ic ? uu[k] : u_cat;
        const bool upd = (!ic) && (uu[k] > umax);
        umax = upd ? uu[k] : umax;
        kmx  = upd ? k : kmx;
    }
    // gumbel-argmax in ratio form: v_c > v_o  <=>  e_o > e_c * rb
    const float e_c = -__logf(u_cat + 1e-30f) + 1e-30f;
    const float e_o = -__logf(umax  + 1e-30f) + 1e-30f;
    const float thr = e_c * c.rb;
    const int samp = (e_o > thr) ? cat : ((e_o < thr) ? kmx : min(cat, kmx));

    // ---- model posterior in exp space ----
    const float scale = c.e_ct1 * __builtin_amdgcn_rcpf(slg);
    float ve_[16];
    float S_all = 0.f;
#pragma unroll
    for (int k = 0; k < 16; ++k) {
        ve_[k] = ek[k] * scale + c.C1;   // exp(evm_k), in (0, 1.1]
        S_all += ve_[k];
    }
    // sum_le via 4 grouped products (4 logs instead of 16); group product
    // >= (1e-7)^4 = 1e-28 > FLT_MIN, no underflow.
    float sum_le = 0.f;
#pragma unroll
    for (int gq = 0; gq < 4; ++gq) {
        const float p = ve_[4*gq] * ve_[4*gq+1] * ve_[4*gq+2] * ve_[4*gq+3];
        sum_le += __logf(p);
    }
    float ve_cat = ve_[0], ve_samp = ve_[0];
#pragma unroll
    for (int k = 0; k < 16; ++k) {
        ve_cat  = (k == cat)  ? ve_[k] : ve_cat;
        ve_samp = (k == samp) ? ve_[k] : ve_samp;
    }
    const float le_cat  = __logf(ve_cat);
    const float le_samp = __logf(ve_samp);
    const float sum_m = c.eqo * (S_all - ve_samp) + c.eqs * ve_samp;
    const float lsem  = __logf(sum_m);

    // ---- true posterior: <=3 distinct values, closed-form ----
    const bool  eq  = (cat == samp);
    const float q_c = eq ? c.qs : c.qo;
    const float w_s = eq ? 0.f : 1.f;
    const float n_o = eq ? 15.f : 14.f;
    const float a  = c.evt_cat + q_c;
    const float bs = c.evt_oth + c.qs;
    const float cc = c.evt_oth + c.qo;
    const float m  = fmaxf(a, fmaxf(bs, cc));
    const float ea = __expf(a - m), eb = __expf(bs - m), ecx = __expf(cc - m);
    const float D  = ea + w_s * eb + n_o * ecx;
    const float lset = m + __logf(D);
    const float rcpD = __builtin_amdgcn_rcpf(D);
    const float lt_c = a - lset, lt_s = bs - lset, lt_o = cc - lset;
    const float p_c = ea * rcpD, p_s = eb * rcpD, p_o = ecx * rcpD;

    const float sum_p_lt = p_c * lt_c + w_s * p_s * lt_s + n_o * p_o * lt_o;
    const float lm_cat  = le_cat  + q_c  - lsem;
    const float lm_samp = le_samp + c.qs - lsem;
    const float sum_lm_oth = (sum_le - le_cat - w_s * le_samp) + n_o * (c.qo - lsem);
    const float sum_p_lm = p_c * lm_cat + w_s * p_s * lm_samp + p_o * sum_lm_oth;
    const float kl  = sum_p_lt - sum_p_lm;
    const float nll = -lm_cat;

    float acc = ((c.t0 ? nll : kl) + c.klp) * (0.5f / 64.0f);

    // ---- numeric branch MSE (tids 0..131071) ----
    if (tid < 64 * 8 * 256) {
        const float d = mnum[tid] - nnum[tid];
        acc += d * d * (0.5f / 131072.f);
    }

    // ---- block reduction ----
    for (int o = 32; o > 0; o >>= 1) acc += __shfl_down(acc, o, 64);
    __shared__ float wsum[4];
    const int wave = threadIdx.x >> 6, lane = threadIdx.x & 63;
    if (lane == 0) wsum[wave] = acc;
    __syncthreads();
    if (threadIdx.x == 0)
        partials[blockIdx.x] = wsum[0] + wsum[1] + wsum[2] + wsum[3];
}

// Kernel 2: deterministic final reduce (graph edge orders it; fence-free,
// atomic-free -- same-address atomics measured ~9-10us at 1024 blocks).
__global__ void reduce_kernel(const float* __restrict__ partials,
                              float* __restrict__ out) {
    float v = partials[threadIdx.x];   // NBLK=1024 threads exactly
    for (int o = 32; o > 0; o >>= 1) v += __shfl_down(v, o, 64);
    __shared__ float wsum[16];
    const int wave = threadIdx.x >> 6, lane = threadIdx.x & 63;
    if (lane == 0) wsum[wave] = v;
    __syncthreads();
    if (threadIdx.x == 0) {
        float s = 0.f;
#pragma unroll
        for (int w = 0; w < 16; ++w) s += wsum[w];
        out[0] = s;
    }
}

extern "C" void kernel_launch(void* const* d_in, const int* in_sizes, int n_in,
                              void* d_out, int out_size, void* d_ws, size_t ws_size,
                              hipStream_t stream) {
    const int*   cats   = (const int*)  d_in[0];
    const float* logits = (const float*)d_in[1];
    const float* mnum   = (const float*)d_in[2];
    const float* nnum   = (const float*)d_in[3];
    const float* unoise = (const float*)d_in[4];
    const int*   tarr   = (const int*)  d_in[5];

    float* partials = (float*)d_ws;

    main_kernel<<<NBLK, NTHR, 0, stream>>>(cats, logits, mnum, nnum, unoise,
                                           tarr, partials);
    reduce_kernel<<<1, NBLK, 0, stream>>>(partials, (float*)d_out);
}